// Round 1
// 378.347 us; speedup vs baseline: 1.1972x; 1.1972x over previous
//
#include <hip/hip_runtime.h>
#include <hip/hip_bf16.h>

using bf16 = __hip_bfloat16;
typedef __bf16 bf16v8 __attribute__((ext_vector_type(8)));
typedef float f32x4 __attribute__((ext_vector_type(4)));

#define HW 4096      // 64*64 spatial per image
#define ROWS 65536   // 16*HW

#define AS1 const __attribute__((address_space(1))) void*
#define AS3 __attribute__((address_space(3))) void*

// ordered-int mapping for float atomicMax
__device__ __forceinline__ int f2oi(float f) { int i = __float_as_int(f); return i >= 0 ? i : i ^ 0x7FFFFFFF; }
__device__ __forceinline__ float oi2f(int i) { return __int_as_float(i >= 0 ? i : i ^ 0x7FFFFFFF); }

// ---------------- zero helper ------------------------------------------------
__global__ void r4_zero(float* __restrict__ p) {
    p[blockIdx.x * 256 + threadIdx.x] = 0.f;
}

// ------- init: BN sums (2048 f) = 0; softmax m/l slots for both branches -----
__global__ void r5_init(float* __restrict__ stats, int* __restrict__ mo2, float* __restrict__ lo2,
                        int* __restrict__ mo3, float* __restrict__ lo3) {
    int i = blockIdx.x * 256 + threadIdx.x;   // 8 blocks * 256 = 2048
    stats[i] = 0.f;
    if (i < 1024) {
        int neg = f2oi(-1e30f);
        mo2[i] = neg; lo2[i] = 0.f;
        mo3[i] = neg; lo3[i] = 0.f;
    }
}

// ------- convert+transpose x: fp32 [b][c=128][n] -> bf16 [b][n][c=128] -------
__global__ void r4_cvt_x(const float* __restrict__ x, bf16* __restrict__ xT) {
    __shared__ bf16 tile[64 * 65];
    int b = blockIdx.z, c0 = blockIdx.y * 64, n0 = blockIdx.x * 64;
    int t = threadIdx.x;
    for (int i = 0; i < 16; i++) {
        int idx = i * 256 + t;
        int cc = idx >> 6, nn = idx & 63;
        tile[nn * 65 + cc] = __float2bfloat16(x[((size_t)(b * 128 + c0 + cc)) * HW + n0 + nn]);
    }
    __syncthreads();
    for (int i = 0; i < 16; i++) {
        int idx = i * 256 + t;
        int nn = idx >> 6, cc = idx & 63;
        xT[((size_t)(b * HW + n0 + nn)) * 128 + c0 + cc] = tile[nn * 65 + cc];
    }
}

// ------- convert the 6 plain weight matrices fp32 -> bf16 (one launch) -------
__global__ void r4_cvt_w(const float* __restrict__ Wsc, const float* __restrict__ W1,
                         const float* __restrict__ Wb0,
                         const float* __restrict__ Wqkv2, const float* __restrict__ Wqkv3,
                         const float* __restrict__ W2, bf16* __restrict__ wbase) {
    int i = blockIdx.x * 256 + threadIdx.x;   // 624 blocks * 256 = 159744 exact
    const float* s; int off;
    if      (i < 32768)  { s = Wsc;   off = i; }
    else if (i < 65536)  { s = W1;    off = i - 32768; }
    else if (i < 69632)  { s = Wb0;   off = i - 65536; }
    else if (i < 81920)  { s = Wqkv2; off = i - 69632; }
    else if (i < 94208)  { s = Wqkv3; off = i - 81920; }
    else                 { s = W2;    off = i - 94208; }
    wbase[i] = __float2bfloat16(s[off]);
}

// ------- pack+convert Wb1 fp32 [o][c][3][3] -> bf16 [tap][o][c] --------------
__global__ void r4_pack3(const float* __restrict__ w, bf16* __restrict__ wp) {
    int i = blockIdx.x * 256 + threadIdx.x;   // 144*256 = 36864 exact
    int tap = i / 4096, rem = i % 4096;
    int o = rem >> 6, c = rem & 63;
    wp[i] = __float2bfloat16(w[(size_t)(o * 64 + c) * 9 + tap]);
}

// ------- bn params: sc/sh per channel from sums (+optional 4-way quarter) ----
__global__ void r6_bnparam(const float* __restrict__ sums,
                           const float* __restrict__ g0, const float* __restrict__ b0,
                           const float* __restrict__ g1, const float* __restrict__ b1,
                           const float* __restrict__ g2, const float* __restrict__ b2,
                           const float* __restrict__ g3, const float* __restrict__ b3,
                           int quarter, float* __restrict__ sc, float* __restrict__ sh) {
    int ch = threadIdx.x;
    const float *gp, *bp; int ci;
    if (quarter) {
        int qi = ch >> 6; ci = ch & 63;
        gp = qi == 0 ? g0 : qi == 1 ? g1 : qi == 2 ? g2 : g3;
        bp = qi == 0 ? b0 : qi == 1 ? b1 : qi == 2 ? b2 : b3;
    } else { gp = g0; bp = b0; ci = ch; }
    float mean = sums[ch] * (1.f / 65536.f);
    float var  = sums[256 + ch] * (1.f / 65536.f) - mean * mean;
    float s = gp[ci] * rsqrtf(var + 1e-5f);
    sc[ch] = s;
    sh[ch] = bp[ci] - mean * s;
}

// ------- in-place bn+relu activation pass (bf16, vectorized) -----------------
__global__ __launch_bounds__(256) void r10_act(bf16* __restrict__ buf,
        const float* __restrict__ sc, const float* __restrict__ sh) {
    __shared__ float scS[256], shS[256];
    int t = threadIdx.x;
    scS[t] = sc[t]; shS[t] = sh[t];
    __syncthreads();
    long base = (long)blockIdx.x * 8192;   // 8 row-groups of 256 ch, x4
    int c0 = (t & 31) * 8;
#pragma unroll
    for (int i = 0; i < 4; i++) {
        long e = base + i * 2048 + t * 8;
        bf16v8 v = *(const bf16v8*)&buf[e];
#pragma unroll
        for (int j = 0; j < 8; j++) {
            float f = (float)v[j] * scS[c0 + j] + shS[c0 + j];
            v[j] = (__bf16)fmaxf(f, 0.f);
        }
        *(bf16v8*)&buf[e] = v;
    }
}

// ===== ga_gemm: 128x128 tile, 4 waves (2x2), 64x64 per wave ==================
// Raw bf16 A (no transform). global_load_lds staging, XOR-swizzled chunks.
// KK in {128, 256}; K staged in 128-wide phases.
template <int KK>
__global__ __launch_bounds__(256) void ga_gemm(
        const bf16* __restrict__ A, int a_stride,
        const bf16* __restrict__ W, int w_stride,
        bf16* __restrict__ out0, bf16* __restrict__ out1, int split,
        int out_stride,
        float* __restrict__ stat0, float* __restrict__ stat1,
        int scol0, int scol1) {
    __shared__ bf16 shmem[2 * 128 * 128];     // As | Ws (linear: gload_lds dest)
    __shared__ float sredS[256], sredQ[256];
    bf16* As = shmem;
    bf16* Ws = shmem + 128 * 128;

    int t = threadIdx.x;
    int wave = t >> 6, lane = t & 63;
    int lo = lane & 15, quad = lane >> 4;
    int wr = wave >> 1, wc = wave & 1;
    int b = blockIdx.z;
    long grow = (long)b * HW + blockIdx.x * 128;
    int o0 = blockIdx.y * 128;
    const bf16* Wb = W + (long)o0 * w_stride;

    f32x4 acc[4][4];
#pragma unroll
    for (int m = 0; m < 4; m++)
#pragma unroll
        for (int n = 0; n < 4; n++) acc[m][n] = (f32x4){0.f, 0.f, 0.f, 0.f};

#pragma unroll
    for (int ph = 0; ph < KK / 128; ph++) {
        int k0 = ph * 128;
        // stage A+W halves: 2048 16B-chunks each, 8 wave-instrs per wave per tensor.
        // LDS linear; global source chunk index swizzled c^(row&7) (rule #21).
#pragma unroll
        for (int j = 0; j < 8; j++) {
            int ci = (j * 4 + wave) * 64 + lane;
            int R = ci >> 4, cc = ci & 15;
            int sw = ((cc ^ (R & 7)) << 3);
            __builtin_amdgcn_global_load_lds(
                (AS1)(A + (grow + R) * (long)a_stride + k0 + sw),
                (AS3)(As + (j * 4 + wave) * 512), 16, 0, 0);
            __builtin_amdgcn_global_load_lds(
                (AS1)(Wb + (long)R * w_stride + k0 + sw),
                (AS3)(Ws + (j * 4 + wave) * 512), 16, 0, 0);
        }
        asm volatile("s_waitcnt vmcnt(0)" ::: "memory");
        __syncthreads();
#pragma unroll
        for (int ks = 0; ks < 128; ks += 32) {
            bf16v8 av[4], wv[4];
#pragma unroll
            for (int m = 0; m < 4; m++) {
                int R = wr * 64 + m * 16 + lo;
                av[m] = *(const bf16v8*)&As[R * 128 + ((((ks >> 3) + quad) ^ (R & 7)) << 3)];
            }
#pragma unroll
            for (int n = 0; n < 4; n++) {
                int R = wc * 64 + n * 16 + lo;
                wv[n] = *(const bf16v8*)&Ws[R * 128 + ((((ks >> 3) + quad) ^ (R & 7)) << 3)];
            }
#pragma unroll
            for (int m = 0; m < 4; m++)
#pragma unroll
                for (int n = 0; n < 4; n++)
                    acc[m][n] = __builtin_amdgcn_mfma_f32_16x16x32_bf16(av[m], wv[n], acc[m][n], 0, 0, 0);
        }
        __syncthreads();   // all reads done before restaging / epilogue reuse
    }

    // epilogue: restage to bf16 tile [128][136] (reuses shmem), then v8 stores
    bf16* Ot = shmem;
#pragma unroll
    for (int m = 0; m < 4; m++)
#pragma unroll
        for (int n = 0; n < 4; n++)
#pragma unroll
            for (int r = 0; r < 4; r++)
                Ot[(wr * 64 + m * 16 + quad * 4 + r) * 136 + wc * 64 + n * 16 + lo] =
                    __float2bfloat16(acc[m][n][r]);
    __syncthreads();
    bool low = o0 < split;
    bf16* op = low ? out0 : out1;
    int oc0 = low ? o0 : o0 - split;
#pragma unroll
    for (int i = 0; i < 8; i++) {
        int u = i * 256 + t;
        int lr = u >> 4, cg = u & 15;
        *(bf16v8*)&op[(grow + lr) * (long)out_stride + oc0 + cg * 8] =
            *(const bf16v8*)&Ot[lr * 136 + cg * 8];
    }
    if (stat0) {
        int c = t & 127, half = t >> 7;
        float s = 0.f, q = 0.f;
#pragma unroll
        for (int r = 0; r < 64; r++) {
            float v = __bfloat162float(Ot[(half * 64 + r) * 136 + c]);
            s += v; q += v * v;
        }
        sredS[t] = s; sredQ[t] = q;
        __syncthreads();
        if (t < 128) {
            float ss = sredS[t] + sredS[t + 128];
            float qq = sredQ[t] + sredQ[t + 128];
            float* st = low ? stat0 : stat1;
            int ci = (low ? scol0 + o0 : scol1 + o0 - split) + c;
            atomicAdd(&st[ci], ss);
            atomicAdd(&st[256 + ci], qq);
        }
    }
}

// ===== gb_gemm: 256x64 tile, 4 waves (4x1), 64x64 per wave, K=64 =============
__global__ __launch_bounds__(256) void gb_gemm(
        const bf16* __restrict__ A, int a_stride,
        const bf16* __restrict__ W, long w_bstride,
        bf16* __restrict__ out, int out_stride,
        float* __restrict__ stat, int scol) {
    __shared__ bf16 shmem[256 * 64 + 64 * 64];
    __shared__ float sredS[256], sredQ[256];
    bf16* As = shmem;
    bf16* Ws = shmem + 256 * 64;

    int t = threadIdx.x;
    int wave = t >> 6, lane = t & 63;
    int lo = lane & 15, quad = lane >> 4;
    int b = blockIdx.z;
    long grow = (long)b * HW + blockIdx.x * 256;
    const bf16* Wb = W + (long)blockIdx.y * 4096 + (long)b * w_bstride;

    f32x4 acc[4][4];
#pragma unroll
    for (int m = 0; m < 4; m++)
#pragma unroll
        for (int n = 0; n < 4; n++) acc[m][n] = (f32x4){0.f, 0.f, 0.f, 0.f};

#pragma unroll
    for (int j = 0; j < 8; j++) {          // A: 256 rows x 8 chunks = 2048
        int ci = (j * 4 + wave) * 64 + lane;
        int R = ci >> 3, cc = ci & 7;
        __builtin_amdgcn_global_load_lds(
            (AS1)(A + (grow + R) * (long)a_stride + ((cc ^ (R & 7)) << 3)),
            (AS3)(As + (j * 4 + wave) * 512), 16, 0, 0);
    }
#pragma unroll
    for (int j = 0; j < 2; j++) {          // W: 64 rows x 8 chunks = 512
        int ci = (j * 4 + wave) * 64 + lane;
        int R = ci >> 3, cc = ci & 7;
        __builtin_amdgcn_global_load_lds(
            (AS1)(Wb + R * 64 + ((cc ^ (R & 7)) << 3)),
            (AS3)(Ws + (j * 4 + wave) * 512), 16, 0, 0);
    }
    asm volatile("s_waitcnt vmcnt(0)" ::: "memory");
    __syncthreads();

#pragma unroll
    for (int ks = 0; ks < 64; ks += 32) {
        bf16v8 av[4], wv[4];
#pragma unroll
        for (int m = 0; m < 4; m++) {
            int R = wave * 64 + m * 16 + lo;
            av[m] = *(const bf16v8*)&As[R * 64 + ((((ks >> 3) + quad) ^ (R & 7)) << 3)];
        }
#pragma unroll
        for (int n = 0; n < 4; n++) {
            int o = n * 16 + lo;
            wv[n] = *(const bf16v8*)&Ws[o * 64 + ((((ks >> 3) + quad) ^ (o & 7)) << 3)];
        }
#pragma unroll
        for (int m = 0; m < 4; m++)
#pragma unroll
            for (int n = 0; n < 4; n++)
                acc[m][n] = __builtin_amdgcn_mfma_f32_16x16x32_bf16(av[m], wv[n], acc[m][n], 0, 0, 0);
    }
    __syncthreads();

    bf16* Ot = shmem;                       // [256][72]
#pragma unroll
    for (int m = 0; m < 4; m++)
#pragma unroll
        for (int n = 0; n < 4; n++)
#pragma unroll
            for (int r = 0; r < 4; r++)
                Ot[(wave * 64 + m * 16 + quad * 4 + r) * 72 + n * 16 + lo] =
                    __float2bfloat16(acc[m][n][r]);
    __syncthreads();
    int oc0 = blockIdx.y * 64;
#pragma unroll
    for (int i = 0; i < 8; i++) {
        int u = i * 256 + t;
        int lr = u >> 3, cg = u & 7;
        *(bf16v8*)&out[(grow + lr) * (long)out_stride + oc0 + cg * 8] =
            *(const bf16v8*)&Ot[lr * 72 + cg * 8];
    }
    if (stat) {
        int c = t & 63, qtr = t >> 6;
        float s = 0.f, q = 0.f;
#pragma unroll
        for (int r = 0; r < 64; r++) {
            float v = __bfloat162float(Ot[(qtr * 64 + r) * 72 + c]);
            s += v; q += v * v;
        }
        sredS[t] = s; sredQ[t] = q;
        __syncthreads();
        if (t < 64) {
            float ss = sredS[t] + sredS[t + 64] + sredS[t + 128] + sredS[t + 192];
            float qq = sredQ[t] + sredQ[t + 64] + sredQ[t + 128] + sredQ[t + 192];
            atomicAdd(&stat[scol + t], ss);
            atomicAdd(&stat[256 + scol + t], qq);
        }
    }
}

// ===== r8 conv3: full LDS staging (input rows pre-activated + 9 tap weights) =
// block = 2 y-rows x 64 out channels; grid (32, 16)
__global__ __launch_bounds__(256) void r8_conv3(
        const bf16* __restrict__ hT, const bf16* __restrict__ wp,
        bf16* __restrict__ obuf, float* __restrict__ stat) {
    __shared__ bf16 As[4 * 66 * 72];     // rows y-1..y+2, x-halo at 0/65, stride 72
    __shared__ bf16 Wt[9 * 64 * 72];     // [tap][o][k] stride 72
    __shared__ float sredS[4][64], sredQ[4][64];

    int t = threadIdx.x;
    int wave = t >> 6, lane = t & 63;
    int lo = lane & 15, quad = lane >> 4;
    int b = blockIdx.y, y0 = blockIdx.x * 2;

    // weights: 9*64*8 = 4608 v8-chunks
#pragma unroll
    for (int i = 0; i < 18; i++) {
        int u = i * 256 + t;
        int tap = u >> 9, rem = u & 511;
        int o = rem >> 3, ck = rem & 7;
        *(bf16v8*)&Wt[tap * 4608 + o * 72 + ck * 8] =
            *(const bf16v8*)(wp + tap * 4096 + o * 64 + ck * 8);
    }
    // input rows: 4 rows x 64 x x 8 chunks = 2048 v8-chunks (already activated)
#pragma unroll
    for (int i = 0; i < 8; i++) {
        int u = i * 256 + t;
        int row = u >> 9, rem = u & 511;
        int xx = rem >> 3, ck = rem & 7;
        int yy = y0 - 1 + row;
        bf16v8 av = (bf16v8){0, 0, 0, 0, 0, 0, 0, 0};
        if (yy >= 0 && yy < 64)
            av = *(const bf16v8*)(hT + ((long)b * HW + yy * 64 + xx) * 256 + 64 + ck * 8);
        *(bf16v8*)&As[row * 4752 + (xx + 1) * 72 + ck * 8] = av;
    }
    if (t < 64) {  // x halos = zero
        int row = t >> 4, side = (t >> 3) & 1, ck = t & 7;
        *(bf16v8*)&As[row * 4752 + (side ? 65 : 0) * 72 + ck * 8] = (bf16v8){0,0,0,0,0,0,0,0};
    }
    __syncthreads();

    f32x4 acc[2][4];
#pragma unroll
    for (int s = 0; s < 2; s++)
#pragma unroll
        for (int ot = 0; ot < 4; ot++) acc[s][ot] = (f32x4){0.f, 0.f, 0.f, 0.f};

#pragma unroll
    for (int tap = 0; tap < 9; tap++) {
        int dy = tap / 3 - 1, dx = tap % 3 - 1;
#pragma unroll
        for (int ks = 0; ks < 64; ks += 32) {
            bf16v8 wv[4];
#pragma unroll
            for (int ot = 0; ot < 4; ot++)
                wv[ot] = *(const bf16v8*)&Wt[tap * 4608 + (ot * 16 + lo) * 72 + ks + quad * 8];
#pragma unroll
            for (int s = 0; s < 2; s++) {
                int pb = wave * 32 + s * 16;
                int yl = pb >> 6, xb = pb & 63;
                bf16v8 av = *(const bf16v8*)&As[(yl + dy + 1) * 4752 + (xb + lo + dx + 1) * 72 + ks + quad * 8];
#pragma unroll
                for (int ot = 0; ot < 4; ot++)
                    acc[s][ot] = __builtin_amdgcn_mfma_f32_16x16x32_bf16(av, wv[ot], acc[s][ot], 0, 0, 0);
            }
        }
    }
    __syncthreads();  // before reusing As as output tile (128 rows x stride 72)

#pragma unroll
    for (int s = 0; s < 2; s++)
#pragma unroll
        for (int ot = 0; ot < 4; ot++)
#pragma unroll
            for (int r = 0; r < 4; r++)
                As[(wave * 32 + s * 16 + quad * 4 + r) * 72 + ot * 16 + lo] =
                    __float2bfloat16(acc[s][ot][r]);
    __syncthreads();

    long grow = (long)b * HW + y0 * 64;
#pragma unroll
    for (int i = 0; i < 4; i++) {
        int u = i * 256 + t;
        int lr = u >> 3, cg = u & 7;
        bf16v8 v = *(const bf16v8*)&As[lr * 72 + cg * 8];
        *(bf16v8*)&obuf[(grow + lr) * 256 + 64 + cg * 8] = v;
    }
    {
        float s = 0.f, q = 0.f;
#pragma unroll
        for (int i = 0; i < 32; i++) {
            float v = __bfloat162float(As[(wave * 32 + i) * 72 + lane]);
            s += v; q += v * v;
        }
        sredS[wave][lane] = s; sredQ[wave][lane] = q;
        __syncthreads();
        if (t < 64) {
            float ss = sredS[0][t] + sredS[1][t] + sredS[2][t] + sredS[3][t];
            float qq = sredQ[0][t] + sredQ[1][t] + sredQ[2][t] + sredQ[3][t];
            atomicAdd(&stat[64 + t], ss);
            atomicAdd(&stat[256 + 64 + t], qq);
        }
    }
}

// ------- per-(b,c) max of k-slice, wide grid + ordered-int atomicMax ---------
__global__ void r5_kmax(const bf16* __restrict__ qkvT, int* __restrict__ mo) {
    __shared__ float red[256];
    int b = blockIdx.y, t = threadIdx.x, c = t & 63, sub = t >> 6;   // 4 subs
    long n0 = (long)blockIdx.x * 128 + sub * 32;
    const bf16* base = qkvT + ((long)b * HW + n0) * 192 + 64 + c;
    float mx = -1e30f;
    for (int n = 0; n < 32; n++)
        mx = fmaxf(mx, __bfloat162float(base[n * 192]));
    red[t] = mx; __syncthreads();
    if (t < 64) {
        float m = fmaxf(fmaxf(red[t], red[t + 64]), fmaxf(red[t + 128], red[t + 192]));
        atomicMax(&mo[b * 64 + t], f2oi(m));
    }
}

// ------- per-(b,c) sum of exp(k - m), wide grid + atomicAdd ------------------
__global__ void r5_ksum(const bf16* __restrict__ qkvT, const int* __restrict__ mo,
                        float* __restrict__ lo_) {
    __shared__ float red[256];
    int b = blockIdx.y, t = threadIdx.x, c = t & 63, sub = t >> 6;
    long n0 = (long)blockIdx.x * 128 + sub * 32;
    float m = oi2f(mo[b * 64 + c]);
    const bf16* base = qkvT + ((long)b * HW + n0) * 192 + 64 + c;
    float s = 0.f;
    for (int n = 0; n < 32; n++)
        s += expf(__bfloat162float(base[n * 192]) - m);
    red[t] = s; __syncthreads();
    if (t < 64) {
        float tot = red[t] + red[t + 64] + red[t + 128] + red[t + 192];
        atomicAdd(&lo_[b * 64 + t], tot);
    }
}

// ------- apply softmax to k, transpose k,v to [b][c][n] (vector reads) -------
__global__ void r6_softapply(const bf16* __restrict__ qkvT,
                             const int* __restrict__ m_in, const float* __restrict__ l_in,
                             bf16* __restrict__ softk, bf16* __restrict__ vcn) {
    __shared__ bf16 lk[64 * 65];
    __shared__ bf16 lv[64 * 65];
    __shared__ float mS[64], ilS[64];
    int b = blockIdx.y, n0 = blockIdx.x * 64;
    int t = threadIdx.x;
    if (t < 64) { mS[t] = oi2f(m_in[b * 64 + t]); ilS[t] = 1.f / l_in[b * 64 + t]; }
    __syncthreads();
    for (int half = 0; half < 2; half++) {
        int r = half * 32 + (t >> 3), cg = t & 7;
        const bf16* row = qkvT + ((long)b * HW + n0 + r) * 192;
        bf16v8 k8 = *(const bf16v8*)(row + 64 + cg * 8);
        bf16v8 v8 = *(const bf16v8*)(row + 128 + cg * 8);
#pragma unroll
        for (int j = 0; j < 8; j++) {
            int c = cg * 8 + j;
            lk[c * 65 + r] = __float2bfloat16(expf((float)k8[j] - mS[c]) * ilS[c]);
            lv[c * 65 + r] = (bf16)v8[j];
        }
    }
    __syncthreads();
    for (int i = 0; i < 16; i++) {
        int idx = i * 256 + t; int c = idx >> 6, r = idx & 63;
        long o = ((long)b * 64 + c) * HW + n0 + r;
        softk[o] = lk[c * 65 + r];
        vcn[o]   = lv[c * 65 + r];
    }
}

// ===== r8 ctx: LDS-staged; ctx[b][c][d] = sum_n sk[c][n] v[d][n] =============
// grid (32, 16): n-chunks of 128
__global__ __launch_bounds__(256) void r8_ctx(
        const bf16* __restrict__ softk, const bf16* __restrict__ vcn,
        float* __restrict__ ctx) {
    __shared__ bf16 Ks[64 * 136];
    __shared__ bf16 Vs[64 * 136];
    int t = threadIdx.x;
    int wave = t >> 6, lane = t & 63;
    int lo = lane & 15, quad = lane >> 4;
    int b = blockIdx.y;
    long n0 = (long)blockIdx.x * 128;
#pragma unroll
    for (int i = 0; i < 4; i++) {
        int u = i * 256 + t;
        int c = u >> 4, ck = u & 15;
        *(bf16v8*)&Ks[c * 136 + ck * 8] = *(const bf16v8*)(softk + ((long)b * 64 + c) * HW + n0 + ck * 8);
        *(bf16v8*)&Vs[c * 136 + ck * 8] = *(const bf16v8*)(vcn + ((long)b * 64 + c) * HW + n0 + ck * 8);
    }
    __syncthreads();

    f32x4 acc[4];
#pragma unroll
    for (int ot = 0; ot < 4; ot++) acc[ot] = (f32x4){0.f, 0.f, 0.f, 0.f};
#pragma unroll
    for (int ks = 0; ks < 128; ks += 32) {
        bf16v8 av = *(const bf16v8*)&Ks[(wave * 16 + lo) * 136 + ks + quad * 8];
#pragma unroll
        for (int ot = 0; ot < 4; ot++) {
            bf16v8 bv = *(const bf16v8*)&Vs[(ot * 16 + lo) * 136 + ks + quad * 8];
            acc[ot] = __builtin_amdgcn_mfma_f32_16x16x32_bf16(av, bv, acc[ot], 0, 0, 0);
        }
    }
#pragma unroll
    for (int ot = 0; ot < 4; ot++) {
#pragma unroll
        for (int r = 0; r < 4; r++) {
            int c = wave * 16 + quad * 4 + r;
            int d = ot * 16 + lo;
            atomicAdd(&ctx[((long)b * 64 + c) * 64 + d], acc[ot][r]);
        }
    }
}

// ===== r9 mproj: M[b][e][c] = sum_d Wp[e][d]*ctx[b][c][d], no inner barriers =
__global__ __launch_bounds__(256) void r9_mproj(
        const float* __restrict__ Wp, const float* __restrict__ ctx,
        bf16* __restrict__ M) {
    __shared__ float ctxS[64 * 68];   // [c][d], stride 68 keeps float4 alignment
    int b = blockIdx.x, t = threadIdx.x;
    int e = t & 63, cg = t >> 6;
#pragma unroll
    for (int i = 0; i < 16; i++) {
        int u = i * 256 + t;
        ctxS[(u >> 6) * 68 + (u & 63)] = ctx[(long)b * 4096 + u];
    }
    float wreg[64];
#pragma unroll
    for (int i = 0; i < 16; i++) {
        float4 v = *(const float4*)&Wp[e * 64 + i * 4];
        wreg[i * 4 + 0] = v.x; wreg[i * 4 + 1] = v.y;
        wreg[i * 4 + 2] = v.z; wreg[i * 4 + 3] = v.w;
    }
    __syncthreads();
#pragma unroll
    for (int ci = 0; ci < 16; ci++) {
        int c = cg * 16 + ci;
        float a = 0.f;
#pragma unroll
        for (int dg = 0; dg < 16; dg++) {
            float4 cv = *(const float4*)&ctxS[c * 68 + dg * 4];
            a += wreg[dg * 4 + 0] * cv.x + wreg[dg * 4 + 1] * cv.y
               + wreg[dg * 4 + 2] * cv.z + wreg[dg * 4 + 3] * cv.w;
        }
        M[(long)b * 4096 + e * 64 + c] = __float2bfloat16(a);
    }
}

// --------- final: relu(bn2(y2) + bnsc(ysc)), write fp32 NCHW -----------------
__global__ void r6_final(const bf16* __restrict__ y2, const bf16* __restrict__ ysc,
                         const float* __restrict__ s2sums, const float* __restrict__ scsums,
                         const float* __restrict__ g2, const float* __restrict__ b2,
                         const float* __restrict__ gsc, const float* __restrict__ bsc,
                         float* __restrict__ out) {
    __shared__ float lo_[64 * 65];
    __shared__ float sc2[64], sh2[64], scc[64], shc[64];
    int b = blockIdx.z, c0 = blockIdx.y * 64, n0 = blockIdx.x * 64;
    int t = threadIdx.x;
    if (t < 64) {
        int ch = c0 + t;
        float m2 = s2sums[ch] * (1.f / 65536.f);
        float v2 = s2sums[256 + ch] * (1.f / 65536.f) - m2 * m2;
        float s = g2[ch] * rsqrtf(v2 + 1e-5f);
        sc2[t] = s; sh2[t] = b2[ch] - m2 * s;
        float mc = scsums[ch] * (1.f / 65536.f);
        float vc = scsums[256 + ch] * (1.f / 65536.f) - mc * mc;
        float s2_ = gsc[ch] * rsqrtf(vc + 1e-5f);
        scc[t] = s2_; shc[t] = bsc[ch] - mc * s2_;
    }
    __syncthreads();
    for (int half = 0; half < 2; half++) {
        int r = half * 32 + (t >> 3), cc = (t & 7) * 8;
        long row = (long)b * HW + n0 + r;
        bf16v8 a8 = *(const bf16v8*)&y2[row * 256 + c0 + cc];
        bf16v8 s8 = *(const bf16v8*)&ysc[row * 256 + c0 + cc];
#pragma unroll
        for (int j = 0; j < 8; j++) {
            int c = cc + j;
            float v = (float)a8[j] * sc2[c] + sh2[c] + (float)s8[j] * scc[c] + shc[c];
            lo_[c * 65 + r] = fmaxf(v, 0.f);
        }
    }
    __syncthreads();
    for (int i = 0; i < 16; i++) {
        int idx = i * 256 + t; int c = idx >> 6, r = idx & 63;
        out[((long)b * 256 + c0 + c) * HW + n0 + r] = lo_[c * 65 + r];
    }
}

extern "C" void kernel_launch(void* const* d_in, const int* in_sizes, int n_in,
                              void* d_out, int out_size, void* d_ws, size_t ws_size,
                              hipStream_t stream) {
    const float* x     = (const float*)d_in[0];
    const float* Wsc   = (const float*)d_in[1];
    const float* gsc   = (const float*)d_in[2];
    const float* bsc   = (const float*)d_in[3];
    const float* W1    = (const float*)d_in[4];
    const float* g1    = (const float*)d_in[5];
    const float* b1    = (const float*)d_in[6];
    const float* Wb0   = (const float*)d_in[7];
    const float* gb0   = (const float*)d_in[8];
    const float* bb0   = (const float*)d_in[9];
    const float* Wb1   = (const float*)d_in[10];
    const float* gb1   = (const float*)d_in[11];
    const float* bb1   = (const float*)d_in[12];
    const float* Wqkv2 = (const float*)d_in[13];
    const float* Wproj2= (const float*)d_in[14];
    const float* ga2   = (const float*)d_in[15];
    const float* ba2   = (const float*)d_in[16];
    const float* Wqkv3 = (const float*)d_in[17];
    const float* Wproj3= (const float*)d_in[18];
    const float* ga3   = (const float*)d_in[19];
    const float* ba3   = (const float*)d_in[20];
    const float* W2    = (const float*)d_in[21];
    const float* g2    = (const float*)d_in[22];
    const float* b2    = (const float*)d_in[23];

    // ---- workspace map ----
    char* ws = (char*)d_ws;
    float* stats = (float*)ws;                 // 2048 f: set0 ysc@0, set1 y1@512, set2 obuf@1024, set3 y2@1536
    int*   mo2   = (int*)(ws + 8192);
    float* lo2   = (float*)(ws + 12288);
    int*   mo3   = (int*)(ws + 16384);
    float* lo3   = (float*)(ws + 20480);
    float* scY1  = (float*)(ws + 24576);       // 256 f
    float* shY1  = (float*)(ws + 25600);
    float* scOb  = (float*)(ws + 26624);
    float* shOb  = (float*)(ws + 27648);
    float* ctx   = (float*)(ws + 28672);       // 262144 B -> 290816
    bf16*  M     = (bf16*)(ws + 290816);       // 131072 B -> 421888
    bf16*  wbase = (bf16*)(ws + 421888);       // 319488 B -> 741376
    bf16*  wsc_b = wbase;                      // [512][128] contiguous (Wsc|W1)
    bf16*  wb0_b = wbase + 65536;
    bf16*  wq2_b = wbase + 69632;
    bf16*  wq3_b = wbase + 81920;
    bf16*  w2_b  = wbase + 94208;
    bf16*  wb1p  = (bf16*)(ws + 741376);       // 73728 B -> 815104
    bf16*  xT    = (bf16*)(ws + 1048576);      // 16 MiB; dead after big gemm
    bf16*  sk    = xT;                         // 8 MiB reuse
    bf16*  vcn   = (bf16*)(ws + 1048576 + 8388608);
    bf16*  ysc   = (bf16*)(ws + 17825792);     // 32 MiB, live to end
    bf16*  y1    = (bf16*)(ws + 51380224);     // 32 MiB
    bf16*  y2    = y1;                         // alias (y1 dead after qkv3 gemm)
    bf16*  obuf  = (bf16*)d_out;               // 32 MiB bf16 scratch in d_out
    bf16*  qkv   = (bf16*)((char*)d_out + 33554432); // 24 MiB

    r5_init<<<dim3(8), 256, 0, stream>>>(stats, mo2, lo2, mo3, lo3);
    r4_cvt_w<<<dim3(624), 256, 0, stream>>>(Wsc, W1, Wb0, Wqkv2, Wqkv3, W2, wbase);
    r4_pack3<<<dim3(144), 256, 0, stream>>>(Wb1, wb1p);
    r4_cvt_x<<<dim3(64, 2, 16), 256, 0, stream>>>(x, xT);

    // conv_sc + conv1 fused (O=512), stats fused (ysc->set0, y1->set1)
    ga_gemm<128><<<dim3(32, 4, 16), 256, 0, stream>>>(
        xT, 128, wsc_b, 128,
        ysc, y1, 256, 256, stats, stats + 512, 0, 0);
    r6_bnparam<<<1, 256, 0, stream>>>(stats + 512, g1, b1, g1, b1, g1, b1, g1, b1, 0, scY1, shY1);
    // pre-activate y1 in place: h = relu(bn(y1)) -- consumers read raw bf16
    r10_act<<<dim3(2048), 256, 0, stream>>>(y1, scY1, shY1);

    // branch 0 (1x1, K=64 on h cols 0..63) and branch 1 (3x3) -> obuf
    gb_gemm<<<dim3(16, 1, 16), 256, 0, stream>>>(
        y1, 256, wb0_b, 0, obuf, 256, stats + 1024, 0);
    r8_conv3<<<dim3(32, 16), 256, 0, stream>>>(y1, wb1p, obuf, stats + 1024);

    // branch 2 (LGA on h cols 128..191) -> obuf cols [128:192)
    gb_gemm<<<dim3(16, 3, 16), 256, 0, stream>>>(
        y1 + 128, 256, wq2_b, 0, qkv, 192, nullptr, 0);
    r5_kmax<<<dim3(32, 16), 256, 0, stream>>>(qkv, mo2);
    r5_ksum<<<dim3(32, 16), 256, 0, stream>>>(qkv, mo2, lo2);
    r6_softapply<<<dim3(64, 16), 256, 0, stream>>>(qkv, mo2, lo2, sk, vcn);
    r4_zero<<<dim3(256), 256, 0, stream>>>(ctx);
    r8_ctx<<<dim3(32, 16), 256, 0, stream>>>(sk, vcn, ctx);
    r9_mproj<<<dim3(16), 256, 0, stream>>>(Wproj2, ctx, M);
    gb_gemm<<<dim3(16, 1, 16), 256, 0, stream>>>(
        qkv, 192, M, 4096, obuf + 128, 256, stats + 1024, 128);

    // branch 3 (LGA on h cols 192..255) -> obuf cols [192:256)
    gb_gemm<<<dim3(16, 3, 16), 256, 0, stream>>>(
        y1 + 192, 256, wq3_b, 0, qkv, 192, nullptr, 0);
    r5_kmax<<<dim3(32, 16), 256, 0, stream>>>(qkv, mo3);
    r5_ksum<<<dim3(32, 16), 256, 0, stream>>>(qkv, mo3, lo3);
    r6_softapply<<<dim3(64, 16), 256, 0, stream>>>(qkv, mo3, lo3, sk, vcn);
    r4_zero<<<dim3(256), 256, 0, stream>>>(ctx);
    r8_ctx<<<dim3(32, 16), 256, 0, stream>>>(sk, vcn, ctx);
    r9_mproj<<<dim3(16), 256, 0, stream>>>(Wproj3, ctx, M);
    gb_gemm<<<dim3(16, 1, 16), 256, 0, stream>>>(
        qkv, 192, M, 4096, obuf + 192, 256, stats + 1024, 192);

    // concat BN params, pre-activate obuf in place, then conv2 (raw input)
    r6_bnparam<<<1, 256, 0, stream>>>(stats + 1024, gb0, bb0, gb1, bb1, ga2, ba2, ga3, ba3, 1, scOb, shOb);
    r10_act<<<dim3(2048), 256, 0, stream>>>(obuf, scOb, shOb);
    ga_gemm<256><<<dim3(32, 2, 16), 256, 0, stream>>>(
        obuf, 256, w2_b, 256,
        y2, y2, 1 << 28, 256, stats + 1536, stats + 1536, 0, 0);

    r6_final<<<dim3(64, 4, 16), 256, 0, stream>>>(y2, ysc, stats + 1536, stats + 0,
                                                  g2, b2, gsc, bsc, (float*)d_out);
}

// Round 3
// 363.678 us; speedup vs baseline: 1.2455x; 1.0403x over previous
//
#include <hip/hip_runtime.h>
#include <hip/hip_bf16.h>

using bf16 = __hip_bfloat16;
typedef __bf16 bf16v8 __attribute__((ext_vector_type(8)));
typedef float f32x4 __attribute__((ext_vector_type(4)));

#define HW 4096      // 64*64 spatial per image
#define ROWS 65536   // 16*HW

#define AS1 const __attribute__((address_space(1))) void*
#define AS3 __attribute__((address_space(3))) void*

// ---------------- zero helper ------------------------------------------------
__global__ void r4_zero(float* __restrict__ p) {
    p[blockIdx.x * 256 + threadIdx.x] = 0.f;
}

// ------- init: BN sums (2048 f) = 0 ------------------------------------------
__global__ void r5_init(float* __restrict__ stats) {
    int i = blockIdx.x * 256 + threadIdx.x;   // 8 blocks * 256 = 2048
    stats[i] = 0.f;
}

// ------- convert+transpose x: fp32 [b][c=128][n] -> bf16 [b][n][c=128] -------
__global__ void r4_cvt_x(const float* __restrict__ x, bf16* __restrict__ xT) {
    __shared__ bf16 tile[64 * 65];
    int b = blockIdx.z, c0 = blockIdx.y * 64, n0 = blockIdx.x * 64;
    int t = threadIdx.x;
    for (int i = 0; i < 16; i++) {
        int idx = i * 256 + t;
        int cc = idx >> 6, nn = idx & 63;
        tile[nn * 65 + cc] = __float2bfloat16(x[((size_t)(b * 128 + c0 + cc)) * HW + n0 + nn]);
    }
    __syncthreads();
    for (int i = 0; i < 16; i++) {
        int idx = i * 256 + t;
        int nn = idx >> 6, cc = idx & 63;
        xT[((size_t)(b * HW + n0 + nn)) * 128 + c0 + cc] = tile[nn * 65 + cc];
    }
}

// ------- convert the 6 plain weight matrices fp32 -> bf16 (one launch) -------
__global__ void r4_cvt_w(const float* __restrict__ Wsc, const float* __restrict__ W1,
                         const float* __restrict__ Wb0,
                         const float* __restrict__ Wqkv2, const float* __restrict__ Wqkv3,
                         const float* __restrict__ W2, bf16* __restrict__ wbase) {
    int i = blockIdx.x * 256 + threadIdx.x;   // 624 blocks * 256 = 159744 exact
    const float* s; int off;
    if      (i < 32768)  { s = Wsc;   off = i; }
    else if (i < 65536)  { s = W1;    off = i - 32768; }
    else if (i < 69632)  { s = Wb0;   off = i - 65536; }
    else if (i < 81920)  { s = Wqkv2; off = i - 69632; }
    else if (i < 94208)  { s = Wqkv3; off = i - 81920; }
    else                 { s = W2;    off = i - 94208; }
    wbase[i] = __float2bfloat16(s[off]);
}

// ------- pack+convert Wb1 fp32 [o][c][3][3] -> bf16 [tap][o][c] --------------
__global__ void r4_pack3(const float* __restrict__ w, bf16* __restrict__ wp) {
    int i = blockIdx.x * 256 + threadIdx.x;   // 144*256 = 36864 exact
    int tap = i / 4096, rem = i % 4096;
    int o = rem >> 6, c = rem & 63;
    wp[i] = __float2bfloat16(w[(size_t)(o * 64 + c) * 9 + tap]);
}

// ------- bn params: sc/sh per channel from sums (+optional 4-way quarter) ----
__global__ void r6_bnparam(const float* __restrict__ sums,
                           const float* __restrict__ g0, const float* __restrict__ b0,
                           const float* __restrict__ g1, const float* __restrict__ b1,
                           const float* __restrict__ g2, const float* __restrict__ b2,
                           const float* __restrict__ g3, const float* __restrict__ b3,
                           int quarter, float* __restrict__ sc, float* __restrict__ sh) {
    int ch = threadIdx.x;
    const float *gp, *bp; int ci;
    if (quarter) {
        int qi = ch >> 6; ci = ch & 63;
        gp = qi == 0 ? g0 : qi == 1 ? g1 : qi == 2 ? g2 : g3;
        bp = qi == 0 ? b0 : qi == 1 ? b1 : qi == 2 ? b2 : b3;
    } else { gp = g0; bp = b0; ci = ch; }
    float mean = sums[ch] * (1.f / 65536.f);
    float var  = sums[256 + ch] * (1.f / 65536.f) - mean * mean;
    float s = gp[ci] * rsqrtf(var + 1e-5f);
    sc[ch] = s;
    sh[ch] = bp[ci] - mean * s;
}

// ------- in-place bn+relu activation pass (bf16, vectorized) -----------------
__global__ __launch_bounds__(256) void r10_act(bf16* __restrict__ buf,
        const float* __restrict__ sc, const float* __restrict__ sh) {
    __shared__ float scS[256], shS[256];
    int t = threadIdx.x;
    scS[t] = sc[t]; shS[t] = sh[t];
    __syncthreads();
    long base = (long)blockIdx.x * 8192;   // 4 chunks of 2048
    int c0 = (t & 31) * 8;
#pragma unroll
    for (int i = 0; i < 4; i++) {
        long e = base + i * 2048 + t * 8;
        bf16v8 v = *(const bf16v8*)&buf[e];
#pragma unroll
        for (int j = 0; j < 8; j++) {
            float f = (float)v[j] * scS[c0 + j] + shS[c0 + j];
            v[j] = (__bf16)fmaxf(f, 0.f);
        }
        *(bf16v8*)&buf[e] = v;
    }
}

// ===== ga_gemm: 128x128 tile, 4 waves (2x2), 64x64 per wave ==================
template <int KK>
__global__ __launch_bounds__(256) void ga_gemm(
        const bf16* __restrict__ A, int a_stride,
        const bf16* __restrict__ W, int w_stride,
        bf16* __restrict__ out0, bf16* __restrict__ out1, int split,
        int out_stride,
        float* __restrict__ stat0, float* __restrict__ stat1,
        int scol0, int scol1) {
    __shared__ bf16 shmem[2 * 128 * 128];     // As | Ws (linear: gload_lds dest)
    __shared__ float sredS[256], sredQ[256];
    bf16* As = shmem;
    bf16* Ws = shmem + 128 * 128;

    int t = threadIdx.x;
    int wave = t >> 6, lane = t & 63;
    int lo = lane & 15, quad = lane >> 4;
    int wr = wave >> 1, wc = wave & 1;
    int b = blockIdx.z;
    long grow = (long)b * HW + blockIdx.x * 128;
    int o0 = blockIdx.y * 128;
    const bf16* Wb = W + (long)o0 * w_stride;

    f32x4 acc[4][4];
#pragma unroll
    for (int m = 0; m < 4; m++)
#pragma unroll
        for (int n = 0; n < 4; n++) acc[m][n] = (f32x4){0.f, 0.f, 0.f, 0.f};

#pragma unroll
    for (int ph = 0; ph < KK / 128; ph++) {
        int k0 = ph * 128;
#pragma unroll
        for (int j = 0; j < 8; j++) {
            int ci = (j * 4 + wave) * 64 + lane;
            int R = ci >> 4, cc = ci & 15;
            int sw = ((cc ^ (R & 7)) << 3);
            __builtin_amdgcn_global_load_lds(
                (AS1)(A + (grow + R) * (long)a_stride + k0 + sw),
                (AS3)(As + (j * 4 + wave) * 512), 16, 0, 0);
            __builtin_amdgcn_global_load_lds(
                (AS1)(Wb + (long)R * w_stride + k0 + sw),
                (AS3)(Ws + (j * 4 + wave) * 512), 16, 0, 0);
        }
        asm volatile("s_waitcnt vmcnt(0)" ::: "memory");
        __syncthreads();
#pragma unroll
        for (int ks = 0; ks < 128; ks += 32) {
            bf16v8 av[4], wv[4];
#pragma unroll
            for (int m = 0; m < 4; m++) {
                int R = wr * 64 + m * 16 + lo;
                av[m] = *(const bf16v8*)&As[R * 128 + ((((ks >> 3) + quad) ^ (R & 7)) << 3)];
            }
#pragma unroll
            for (int n = 0; n < 4; n++) {
                int R = wc * 64 + n * 16 + lo;
                wv[n] = *(const bf16v8*)&Ws[R * 128 + ((((ks >> 3) + quad) ^ (R & 7)) << 3)];
            }
#pragma unroll
            for (int m = 0; m < 4; m++)
#pragma unroll
                for (int n = 0; n < 4; n++)
                    acc[m][n] = __builtin_amdgcn_mfma_f32_16x16x32_bf16(av[m], wv[n], acc[m][n], 0, 0, 0);
        }
        __syncthreads();
    }

    bf16* Ot = shmem;
#pragma unroll
    for (int m = 0; m < 4; m++)
#pragma unroll
        for (int n = 0; n < 4; n++)
#pragma unroll
            for (int r = 0; r < 4; r++)
                Ot[(wr * 64 + m * 16 + quad * 4 + r) * 136 + wc * 64 + n * 16 + lo] =
                    __float2bfloat16(acc[m][n][r]);
    __syncthreads();
    bool low = o0 < split;
    bf16* op = low ? out0 : out1;
    int oc0 = low ? o0 : o0 - split;
#pragma unroll
    for (int i = 0; i < 8; i++) {
        int u = i * 256 + t;
        int lr = u >> 4, cg = u & 15;
        *(bf16v8*)&op[(grow + lr) * (long)out_stride + oc0 + cg * 8] =
            *(const bf16v8*)&Ot[lr * 136 + cg * 8];
    }
    if (stat0) {
        int c = t & 127, half = t >> 7;
        float s = 0.f, q = 0.f;
#pragma unroll
        for (int r = 0; r < 64; r++) {
            float v = __bfloat162float(Ot[(half * 64 + r) * 136 + c]);
            s += v; q += v * v;
        }
        sredS[t] = s; sredQ[t] = q;
        __syncthreads();
        if (t < 128) {
            float ss = sredS[t] + sredS[t + 128];
            float qq = sredQ[t] + sredQ[t + 128];
            float* st = low ? stat0 : stat1;
            int ci = (low ? scol0 + o0 : scol1 + o0 - split) + c;
            atomicAdd(&st[ci], ss);
            atomicAdd(&st[256 + ci], qq);
        }
    }
}

// ===== gb_gemm: 256x64 tile, 4 waves (4x1), 64x64 per wave, K=64 =============
__global__ __launch_bounds__(256) void gb_gemm(
        const bf16* __restrict__ A, int a_stride,
        const bf16* __restrict__ W, long w_bstride,
        bf16* __restrict__ out, int out_stride,
        float* __restrict__ stat, int scol) {
    __shared__ bf16 shmem[256 * 64 + 64 * 64];
    __shared__ float sredS[256], sredQ[256];
    bf16* As = shmem;
    bf16* Ws = shmem + 256 * 64;

    int t = threadIdx.x;
    int wave = t >> 6, lane = t & 63;
    int lo = lane & 15, quad = lane >> 4;
    int b = blockIdx.z;
    long grow = (long)b * HW + blockIdx.x * 256;
    const bf16* Wb = W + (long)blockIdx.y * 4096 + (long)b * w_bstride;

    f32x4 acc[4][4];
#pragma unroll
    for (int m = 0; m < 4; m++)
#pragma unroll
        for (int n = 0; n < 4; n++) acc[m][n] = (f32x4){0.f, 0.f, 0.f, 0.f};

#pragma unroll
    for (int j = 0; j < 8; j++) {          // A: 256 rows x 8 chunks = 2048
        int ci = (j * 4 + wave) * 64 + lane;
        int R = ci >> 3, cc = ci & 7;
        __builtin_amdgcn_global_load_lds(
            (AS1)(A + (grow + R) * (long)a_stride + ((cc ^ (R & 7)) << 3)),
            (AS3)(As + (j * 4 + wave) * 512), 16, 0, 0);
    }
#pragma unroll
    for (int j = 0; j < 2; j++) {          // W: 64 rows x 8 chunks = 512
        int ci = (j * 4 + wave) * 64 + lane;
        int R = ci >> 3, cc = ci & 7;
        __builtin_amdgcn_global_load_lds(
            (AS1)(Wb + R * 64 + ((cc ^ (R & 7)) << 3)),
            (AS3)(Ws + (j * 4 + wave) * 512), 16, 0, 0);
    }
    asm volatile("s_waitcnt vmcnt(0)" ::: "memory");
    __syncthreads();

#pragma unroll
    for (int ks = 0; ks < 64; ks += 32) {
        bf16v8 av[4], wv[4];
#pragma unroll
        for (int m = 0; m < 4; m++) {
            int R = wave * 64 + m * 16 + lo;
            av[m] = *(const bf16v8*)&As[R * 64 + ((((ks >> 3) + quad) ^ (R & 7)) << 3)];
        }
#pragma unroll
        for (int n = 0; n < 4; n++) {
            int o = n * 16 + lo;
            wv[n] = *(const bf16v8*)&Ws[o * 64 + ((((ks >> 3) + quad) ^ (o & 7)) << 3)];
        }
#pragma unroll
        for (int m = 0; m < 4; m++)
#pragma unroll
            for (int n = 0; n < 4; n++)
                acc[m][n] = __builtin_amdgcn_mfma_f32_16x16x32_bf16(av[m], wv[n], acc[m][n], 0, 0, 0);
    }
    __syncthreads();

    bf16* Ot = shmem;                       // [256][72]
#pragma unroll
    for (int m = 0; m < 4; m++)
#pragma unroll
        for (int n = 0; n < 4; n++)
#pragma unroll
            for (int r = 0; r < 4; r++)
                Ot[(wave * 64 + m * 16 + quad * 4 + r) * 72 + n * 16 + lo] =
                    __float2bfloat16(acc[m][n][r]);
    __syncthreads();
    int oc0 = blockIdx.y * 64;
#pragma unroll
    for (int i = 0; i < 8; i++) {
        int u = i * 256 + t;
        int lr = u >> 3, cg = u & 7;
        *(bf16v8*)&out[(grow + lr) * (long)out_stride + oc0 + cg * 8] =
            *(const bf16v8*)&Ot[lr * 72 + cg * 8];
    }
    if (stat) {
        int c = t & 63, qtr = t >> 6;
        float s = 0.f, q = 0.f;
#pragma unroll
        for (int r = 0; r < 64; r++) {
            float v = __bfloat162float(Ot[(qtr * 64 + r) * 72 + c]);
            s += v; q += v * v;
        }
        sredS[t] = s; sredQ[t] = q;
        __syncthreads();
        if (t < 64) {
            float ss = sredS[t] + sredS[t + 64] + sredS[t + 128] + sredS[t + 192];
            float qq = sredQ[t] + sredQ[t + 64] + sredQ[t + 128] + sredQ[t + 192];
            atomicAdd(&stat[scol + t], ss);
            atomicAdd(&stat[256 + scol + t], qq);
        }
    }
}

// ===== r12 conv3: 4 y-rows/block, 64x64 wave tile, gload_lds staging =========
// grid (16,16): blockIdx.x = y-block, blockIdx.y = b. 256 blocks = 1/CU.
__global__ __launch_bounds__(256) void r12_conv3(
        const bf16* __restrict__ hT, const bf16* __restrict__ wp,
        bf16* __restrict__ obuf, float* __restrict__ stat) {
    __shared__ bf16 As[6 * 66 * 64];     // [yr][x+1][64], halo cols 0 & 65; 50688 B
    __shared__ bf16 Wt[9 * 64 * 64];     // [tap][o][64]; 73728 B
    __shared__ float sredS[256], sredQ[256];

    int t = threadIdx.x;
    int wave = t >> 6, lane = t & 63;
    int lo = lane & 15, quad = lane >> 4;
    int b = blockIdx.y, y0 = blockIdx.x * 4;

    // stage weights: 4608 chunks = 72 wave-instrs, src chunk swizzled by o&7
#pragma unroll
    for (int j = 0; j < 18; j++) {
        int i = j * 4 + wave;
        int ci = i * 64 + lane;
        int tap = ci >> 9, rem = ci & 511, o = rem >> 3, ck = rem & 7;
        __builtin_amdgcn_global_load_lds(
            (AS1)(wp + tap * 4096 + o * 64 + ((ck ^ (o & 7)) << 3)),
            (AS3)(Wt + i * 512), 16, 0, 0);
    }
    // stage input rows y0-1..y0+4: one row = 8 KiB = 8 wave-instrs; 48 total.
    // i in [0,48): row = i>>3 (0..5), seg = i&7; x = seg*8 + (lane>>3).
    // LDS[row][x+1][ck] = src[x][ck ^ (x&7)]  (rule #21, read applies same XOR)
#pragma unroll
    for (int j = 0; j < 12; j++) {
        int i = j * 4 + wave;            // 0..47
        int row = i >> 3, seg = i & 7;
        int yy = y0 - 1 + row;
        if (yy >= 0 && yy < 64) {
            int xg = seg * 8 + (lane >> 3), ck = lane & 7;
            __builtin_amdgcn_global_load_lds(
                (AS1)(hT + ((long)b * HW + yy * 64 + xg) * 256 + 64 + ((ck ^ (xg & 7)) << 3)),
                (AS3)(As + row * 4224 + 64 + seg * 512), 16, 0, 0);
        } else {
            *(bf16v8*)&As[row * 4224 + 64 + seg * 512 + lane * 8] = (bf16v8){0,0,0,0,0,0,0,0};
        }
    }
    if (t < 96) {   // x halos (cols 0 and 65 of each of 6 rows)
        int yr = t >> 4, side = (t >> 3) & 1, ck = t & 7;
        *(bf16v8*)&As[yr * 4224 + (side ? 65 : 0) * 64 + ck * 8] = (bf16v8){0,0,0,0,0,0,0,0};
    }
    asm volatile("s_waitcnt vmcnt(0)" ::: "memory");
    __syncthreads();

    f32x4 acc[4][4];   // [m spatial 16][ot out 16]
#pragma unroll
    for (int m = 0; m < 4; m++)
#pragma unroll
        for (int n = 0; n < 4; n++) acc[m][n] = (f32x4){0.f, 0.f, 0.f, 0.f};

#pragma unroll
    for (int tap = 0; tap < 9; tap++) {
        int dy = tap / 3 - 1, dx = tap % 3 - 1;
        int yr = wave + 1 + dy;
#pragma unroll
        for (int ks8 = 0; ks8 < 8; ks8 += 4) {
            int kk = ks8 + quad;
            bf16v8 wv[4];
#pragma unroll
            for (int ot = 0; ot < 4; ot++) {
                int o = ot * 16 + lo;
                wv[ot] = *(const bf16v8*)&Wt[tap * 4096 + o * 64 + ((kk ^ (o & 7)) << 3)];
            }
#pragma unroll
            for (int m = 0; m < 4; m++) {
                int xp = m * 16 + lo + dx;
                bf16v8 av = *(const bf16v8*)&As[yr * 4224 + (xp + 1) * 64 + ((kk ^ (xp & 7)) << 3)];
#pragma unroll
                for (int ot = 0; ot < 4; ot++)
                    acc[m][ot] = __builtin_amdgcn_mfma_f32_16x16x32_bf16(av, wv[ot], acc[m][ot], 0, 0, 0);
            }
        }
    }
    __syncthreads();

    bf16* Ot = As;                        // [256][72] = 36864 B, fits
#pragma unroll
    for (int m = 0; m < 4; m++)
#pragma unroll
        for (int ot = 0; ot < 4; ot++)
#pragma unroll
            for (int r = 0; r < 4; r++)
                Ot[(wave * 64 + m * 16 + quad * 4 + r) * 72 + ot * 16 + lo] =
                    __float2bfloat16(acc[m][ot][r]);
    __syncthreads();

    long grow = (long)b * HW + y0 * 64;
#pragma unroll
    for (int i = 0; i < 8; i++) {
        int u = i * 256 + t;
        int lr = u >> 3, cg = u & 7;
        *(bf16v8*)&obuf[(grow + lr) * 256 + 64 + cg * 8] = *(const bf16v8*)&Ot[lr * 72 + cg * 8];
    }
    {
        int c = t & 63, qtr = t >> 6;
        float s = 0.f, q = 0.f;
#pragma unroll
        for (int r = 0; r < 64; r++) {
            float v = __bfloat162float(Ot[(qtr * 64 + r) * 72 + c]);
            s += v; q += v * v;
        }
        sredS[t] = s; sredQ[t] = q;
        __syncthreads();
        if (t < 64) {
            float ss = sredS[t] + sredS[t + 64] + sredS[t + 128] + sredS[t + 192];
            float qq = sredQ[t] + sredQ[t + 64] + sredQ[t + 128] + sredQ[t + 192];
            atomicAdd(&stat[64 + t], ss);
            atomicAdd(&stat[256 + 64 + t], qq);
        }
    }
}

// ------- single-pass k stats: per-block local max + sumexp partials ----------
// grid (32, 16): 128-n chunk per block
__global__ __launch_bounds__(256) void r11_kstat(
        const bf16* __restrict__ qkvT, float* __restrict__ mpart, float* __restrict__ spart) {
    __shared__ float red[2048];          // [rg 32][c 64]
    __shared__ float mlocS[64];
    int t = threadIdx.x;
    int cg = t & 7, rg = t >> 3;
    int b = blockIdx.y, bx = blockIdx.x;
    long n0 = (long)bx * 128;
    float mx[8];
#pragma unroll
    for (int j = 0; j < 8; j++) mx[j] = -1e30f;
#pragma unroll
    for (int s = 0; s < 4; s++) {
        int r = s * 32 + rg;
        bf16v8 k8 = *(const bf16v8*)(qkvT + ((long)b * HW + n0 + r) * 192 + 64 + cg * 8);
#pragma unroll
        for (int j = 0; j < 8; j++) mx[j] = fmaxf(mx[j], (float)k8[j]);
    }
#pragma unroll
    for (int j = 0; j < 8; j++) red[rg * 64 + cg * 8 + j] = mx[j];
    __syncthreads();
    if (t < 64) {
        float m = -1e30f;
#pragma unroll
        for (int i = 0; i < 32; i++) m = fmaxf(m, red[i * 64 + t]);
        mlocS[t] = m;
        mpart[((long)b * 32 + bx) * 64 + t] = m;
    }
    __syncthreads();
    float sm[8];
#pragma unroll
    for (int j = 0; j < 8; j++) sm[j] = 0.f;
#pragma unroll
    for (int s = 0; s < 4; s++) {
        int r = s * 32 + rg;
        bf16v8 k8 = *(const bf16v8*)(qkvT + ((long)b * HW + n0 + r) * 192 + 64 + cg * 8);
#pragma unroll
        for (int j = 0; j < 8; j++) sm[j] += expf((float)k8[j] - mlocS[cg * 8 + j]);
    }
    __syncthreads();
#pragma unroll
    for (int j = 0; j < 8; j++) red[rg * 64 + cg * 8 + j] = sm[j];
    __syncthreads();
    if (t < 64) {
        float s = 0.f;
#pragma unroll
        for (int i = 0; i < 32; i++) s += red[i * 64 + t];
        spart[((long)b * 32 + bx) * 64 + t] = s;
    }
}

// ------- combine partials -> global m, 1/l (grid 4 x 256) --------------------
__global__ void r11_kred(const float* __restrict__ mpart, const float* __restrict__ spart,
                         float* __restrict__ mfin, float* __restrict__ ilfin) {
    int g = blockIdx.x * 256 + threadIdx.x;   // 1024 = 16 b * 64 c
    int b = g >> 6, c = g & 63;
    float m = -1e30f;
    for (int i = 0; i < 32; i++) m = fmaxf(m, mpart[((long)b * 32 + i) * 64 + c]);
    float l = 0.f;
    for (int i = 0; i < 32; i++)
        l += spart[((long)b * 32 + i) * 64 + c] * expf(mpart[((long)b * 32 + i) * 64 + c] - m);
    mfin[g] = m;
    ilfin[g] = 1.f / l;
}

// ===== fused soft+ctx: ctxraw[b][c][d] = sum_n exp(k[c][n]-m_c) v[d][n] ======
// grid (32, 16): n-chunks of 128. 1/l deferred to mproj.
__global__ __launch_bounds__(256) void r11_softctx(
        const bf16* __restrict__ qkvT, const float* __restrict__ mfin,
        float* __restrict__ ctx) {
    __shared__ bf16 Ks[64 * 136];
    __shared__ bf16 Vs[64 * 136];
    __shared__ float mS[64];
    int t = threadIdx.x;
    int wave = t >> 6, lane = t & 63;
    int lo = lane & 15, quad = lane >> 4;
    int b = blockIdx.y;
    long n0 = (long)blockIdx.x * 128;
    if (t < 64) mS[t] = mfin[b * 64 + t];
    __syncthreads();
#pragma unroll
    for (int sub = 0; sub < 4; sub++) {
        int r = sub * 32 + (t >> 3), cg = t & 7;
        const bf16* row = qkvT + ((long)b * HW + n0 + r) * 192;
        bf16v8 k8 = *(const bf16v8*)(row + 64 + cg * 8);
        bf16v8 v8 = *(const bf16v8*)(row + 128 + cg * 8);
#pragma unroll
        for (int j = 0; j < 8; j++) {
            int c = cg * 8 + j;
            Ks[c * 136 + r] = __float2bfloat16(expf((float)k8[j] - mS[c]));
            Vs[c * 136 + r] = (bf16)v8[j];
        }
    }
    __syncthreads();

    f32x4 acc[4];
#pragma unroll
    for (int ot = 0; ot < 4; ot++) acc[ot] = (f32x4){0.f, 0.f, 0.f, 0.f};
#pragma unroll
    for (int ks = 0; ks < 128; ks += 32) {
        bf16v8 av = *(const bf16v8*)&Ks[(wave * 16 + lo) * 136 + ks + quad * 8];
#pragma unroll
        for (int ot = 0; ot < 4; ot++) {
            bf16v8 bv = *(const bf16v8*)&Vs[(ot * 16 + lo) * 136 + ks + quad * 8];
            acc[ot] = __builtin_amdgcn_mfma_f32_16x16x32_bf16(av, bv, acc[ot], 0, 0, 0);
        }
    }
#pragma unroll
    for (int ot = 0; ot < 4; ot++) {
#pragma unroll
        for (int r = 0; r < 4; r++) {
            int c = wave * 16 + quad * 4 + r;
            int d = ot * 16 + lo;
            atomicAdd(&ctx[((long)b * 64 + c) * 64 + d], acc[ot][r]);
        }
    }
}

// ===== r9 mproj: M[b][e][c] = il[c] * sum_d Wp[e][d]*ctx[b][c][d] ============
// grid (16, 4): block handles 16 c-rows
__global__ __launch_bounds__(256) void r9_mproj(
        const float* __restrict__ Wp, const float* __restrict__ ctx,
        const float* __restrict__ ilfin, bf16* __restrict__ M) {
    __shared__ float ctxS[16 * 68];
    __shared__ float ilS[16];
    int b = blockIdx.x, qq = blockIdx.y, t = threadIdx.x;
    int e = t & 63, cg = t >> 6;
#pragma unroll
    for (int i = 0; i < 4; i++) {
        int u = i * 256 + t;
        int c_l = u >> 6, d = u & 63;
        ctxS[c_l * 68 + d] = ctx[((long)b * 64 + qq * 16 + c_l) * 64 + d];
    }
    if (t < 16) ilS[t] = ilfin[b * 64 + qq * 16 + t];
    float wreg[64];
#pragma unroll
    for (int i = 0; i < 16; i++) {
        float4 v = *(const float4*)&Wp[e * 64 + i * 4];
        wreg[i * 4 + 0] = v.x; wreg[i * 4 + 1] = v.y;
        wreg[i * 4 + 2] = v.z; wreg[i * 4 + 3] = v.w;
    }
    __syncthreads();
#pragma unroll
    for (int ci = 0; ci < 4; ci++) {
        int c_l = cg * 4 + ci;
        float a = 0.f;
#pragma unroll
        for (int dg = 0; dg < 16; dg++) {
            float4 cv = *(const float4*)&ctxS[c_l * 68 + dg * 4];
            a += wreg[dg * 4 + 0] * cv.x + wreg[dg * 4 + 1] * cv.y
               + wreg[dg * 4 + 2] * cv.z + wreg[dg * 4 + 3] * cv.w;
        }
        M[(long)b * 4096 + e * 64 + qq * 16 + c_l] = __float2bfloat16(a * ilS[c_l]);
    }
}

// --------- final: relu(bn2(y2) + bnsc(ysc)), write fp32 NCHW -----------------
__global__ void r6_final(const bf16* __restrict__ y2, const bf16* __restrict__ ysc,
                         const float* __restrict__ s2sums, const float* __restrict__ scsums,
                         const float* __restrict__ g2, const float* __restrict__ b2,
                         const float* __restrict__ gsc, const float* __restrict__ bsc,
                         float* __restrict__ out) {
    __shared__ float lo_[64 * 65];
    __shared__ float sc2[64], sh2[64], scc[64], shc[64];
    int b = blockIdx.z, c0 = blockIdx.y * 64, n0 = blockIdx.x * 64;
    int t = threadIdx.x;
    if (t < 64) {
        int ch = c0 + t;
        float m2 = s2sums[ch] * (1.f / 65536.f);
        float v2 = s2sums[256 + ch] * (1.f / 65536.f) - m2 * m2;
        float s = g2[ch] * rsqrtf(v2 + 1e-5f);
        sc2[t] = s; sh2[t] = b2[ch] - m2 * s;
        float mc = scsums[ch] * (1.f / 65536.f);
        float vc = scsums[256 + ch] * (1.f / 65536.f) - mc * mc;
        float s2_ = gsc[ch] * rsqrtf(vc + 1e-5f);
        scc[t] = s2_; shc[t] = bsc[ch] - mc * s2_;
    }
    __syncthreads();
    for (int half = 0; half < 2; half++) {
        int r = half * 32 + (t >> 3), cc = (t & 7) * 8;
        long row = (long)b * HW + n0 + r;
        bf16v8 a8 = *(const bf16v8*)&y2[row * 256 + c0 + cc];
        bf16v8 s8 = *(const bf16v8*)&ysc[row * 256 + c0 + cc];
#pragma unroll
        for (int j = 0; j < 8; j++) {
            int c = cc + j;
            float v = (float)a8[j] * sc2[c] + sh2[c] + (float)s8[j] * scc[c] + shc[c];
            lo_[c * 65 + r] = fmaxf(v, 0.f);
        }
    }
    __syncthreads();
    for (int i = 0; i < 16; i++) {
        int idx = i * 256 + t; int c = idx >> 6, r = idx & 63;
        out[((long)b * 256 + c0 + c) * HW + n0 + r] = lo_[c * 65 + r];
    }
}

extern "C" void kernel_launch(void* const* d_in, const int* in_sizes, int n_in,
                              void* d_out, int out_size, void* d_ws, size_t ws_size,
                              hipStream_t stream) {
    const float* x     = (const float*)d_in[0];
    const float* Wsc   = (const float*)d_in[1];
    const float* gsc   = (const float*)d_in[2];
    const float* bsc   = (const float*)d_in[3];
    const float* W1    = (const float*)d_in[4];
    const float* g1    = (const float*)d_in[5];
    const float* b1    = (const float*)d_in[6];
    const float* Wb0   = (const float*)d_in[7];
    const float* gb0   = (const float*)d_in[8];
    const float* bb0   = (const float*)d_in[9];
    const float* Wb1   = (const float*)d_in[10];
    const float* gb1   = (const float*)d_in[11];
    const float* bb1   = (const float*)d_in[12];
    const float* Wqkv2 = (const float*)d_in[13];
    const float* Wproj2= (const float*)d_in[14];
    const float* ga2   = (const float*)d_in[15];
    const float* ba2   = (const float*)d_in[16];
    const float* Wqkv3 = (const float*)d_in[17];
    const float* Wproj3= (const float*)d_in[18];
    const float* ga3   = (const float*)d_in[19];
    const float* ba3   = (const float*)d_in[20];
    const float* W2    = (const float*)d_in[21];
    const float* g2    = (const float*)d_in[22];
    const float* b2    = (const float*)d_in[23];

    // ---- workspace map ----
    char* ws = (char*)d_ws;
    float* stats = (float*)ws;                 // 2048 f
    float* scY1  = (float*)(ws + 8192);
    float* shY1  = (float*)(ws + 9216);
    float* scOb  = (float*)(ws + 10240);
    float* shOb  = (float*)(ws + 11264);
    float* mfin  = (float*)(ws + 12288);       // 1024 f
    float* ilfin = (float*)(ws + 16384);       // 1024 f
    float* mpart = (float*)(ws + 20480);       // 128 KiB, aliased with ctx
    float* spart = (float*)(ws + 20480 + 131072);
    float* ctx   = (float*)(ws + 20480);       // 256 KiB (partials dead after kred)
    bf16*  M     = (bf16*)(ws + 282624);       // 131072 B -> 413696
    bf16*  wbase = (bf16*)(ws + 413696);       // 319488 B -> 733184
    bf16*  wsc_b = wbase;                      // [512][128] (Wsc|W1)
    bf16*  wb0_b = wbase + 65536;
    bf16*  wq2_b = wbase + 69632;
    bf16*  wq3_b = wbase + 81920;
    bf16*  w2_b  = wbase + 94208;
    bf16*  wb1p  = (bf16*)(ws + 733184);       // 73728 B -> 806912
    bf16*  xT    = (bf16*)(ws + 1048576);      // 16 MiB; dead after big gemm
    bf16*  ysc   = (bf16*)(ws + 17825792);     // 32 MiB, live to end
    bf16*  y1    = (bf16*)(ws + 51380224);     // 32 MiB
    bf16*  y2    = y1;                         // alias (y1 dead after qkv3 gemm)
    bf16*  obuf  = (bf16*)d_out;               // 32 MiB bf16 scratch in d_out
    bf16*  qkv   = (bf16*)((char*)d_out + 33554432); // 24 MiB

    r5_init<<<dim3(8), 256, 0, stream>>>(stats);
    r4_cvt_w<<<dim3(624), 256, 0, stream>>>(Wsc, W1, Wb0, Wqkv2, Wqkv3, W2, wbase);
    r4_pack3<<<dim3(144), 256, 0, stream>>>(Wb1, wb1p);
    r4_cvt_x<<<dim3(64, 2, 16), 256, 0, stream>>>(x, xT);

    // conv_sc + conv1 fused (O=512), stats fused (ysc->set0, y1->set1)
    ga_gemm<128><<<dim3(32, 4, 16), 256, 0, stream>>>(
        xT, 128, wsc_b, 128,
        ysc, y1, 256, 256, stats, stats + 512, 0, 0);
    r6_bnparam<<<1, 256, 0, stream>>>(stats + 512, g1, b1, g1, b1, g1, b1, g1, b1, 0, scY1, shY1);
    r10_act<<<dim3(2048), 256, 0, stream>>>(y1, scY1, shY1);

    // branch 0 (1x1, K=64 on h cols 0..63) and branch 1 (3x3) -> obuf
    gb_gemm<<<dim3(16, 1, 16), 256, 0, stream>>>(
        y1, 256, wb0_b, 0, obuf, 256, stats + 1024, 0);
    r12_conv3<<<dim3(16, 16), 256, 0, stream>>>(y1, wb1p, obuf, stats + 1024);

    // branch 2 (LGA on h cols 128..191) -> obuf cols [128:192)
    gb_gemm<<<dim3(16, 3, 16), 256, 0, stream>>>(
        y1 + 128, 256, wq2_b, 0, qkv, 192, nullptr, 0);
    r11_kstat<<<dim3(32, 16), 256, 0, stream>>>(qkv, mpart, spart);
    r11_kred<<<dim3(4), 256, 0, stream>>>(mpart, spart, mfin, ilfin);
    r4_zero<<<dim3(256), 256, 0, stream>>>(ctx);
    r11_softctx<<<dim3(32, 16), 256, 0, stream>>>(qkv, mfin, ctx);
    r9_mproj<<<dim3(16, 4), 256, 0, stream>>>(Wproj2, ctx, ilfin, M);
    gb_gemm<<<dim3(16, 1, 16), 256, 0, stream>>>(
        qkv, 192, M, 4096, obuf + 128, 256, stats + 1024, 128);

    // branch 3 (LGA on h cols 192..255) -> obuf cols [192:256)
    gb_gemm<<<dim3(16, 3, 16), 256, 0, stream>>>(
        y1 + 192, 256, wq3_b, 0, qkv, 192, nullptr, 0);
    r11_kstat<<<dim3(32, 16), 256, 0, stream>>>(qkv, mpart, spart);
    r11_kred<<<dim3(4), 256, 0, stream>>>(mpart, spart, mfin, ilfin);
    r4_zero<<<dim3(256), 256, 0, stream>>>(ctx);
    r11_softctx<<<dim3(32, 16), 256, 0, stream>>>(qkv, mfin, ctx);
    r9_mproj<<<dim3(16, 4), 256, 0, stream>>>(Wproj3, ctx, ilfin, M);
    gb_gemm<<<dim3(16, 1, 16), 256, 0, stream>>>(
        qkv, 192, M, 4096, obuf + 192, 256, stats + 1024, 192);

    // concat BN params, pre-activate obuf in place, then conv2 (raw input)
    r6_bnparam<<<1, 256, 0, stream>>>(stats + 1024, gb0, bb0, gb1, bb1, ga2, ba2, ga3, ba3, 1, scOb, shOb);
    r10_act<<<dim3(2048), 256, 0, stream>>>(obuf, scOb, shOb);
    ga_gemm<256><<<dim3(32, 2, 16), 256, 0, stream>>>(
        obuf, 256, w2_b, 256,
        y2, y2, 1 << 28, 256, stats + 1536, stats + 1536, 0, 0);

    r6_final<<<dim3(64, 4, 16), 256, 0, stream>>>(y2, ysc, stats + 1536, stats + 0,
                                                  g2, b2, gsc, bsc, (float*)d_out);
}